// Round 9
// baseline (332.271 us; speedup 1.0000x reference)
//
#include <hip/hip_runtime.h>

// ---------------------------------------------------------------------------
// Capsule cell, bf16-MFMA v3.
//   conv0 (1x1, fp32 VALU)          -> h0t  bf16 [B][L][64]
//   conv1 (k=9, MFMA, barrier-free) -> h1   fp32 [B][L][512]
//   squash                          -> h1sq bf16 [b][n][ln][512] (contig rows)
//   conv2 (k=3x512, MFMA, v3)       -> V    fp32 [B][LN][N][256]
//   routing (3 iters, fp32)         -> out  [B][LN*16][16]
// v3: A-operands (weights) read DIRECTLY from L2-resident w1tb/w2p (16-row x
// 64B pattern = full 128B lines) -> no W staging, conv1 main loop barrier-free.
// conv2 LDS = Hc only (33 KB), staged via pre-swizzled per-lane global src
// (rule #21: linear gload_lds dest + slot^(row&7) on BOTH source and read).
// ---------------------------------------------------------------------------

#define LL    2048
#define NCAP  8
#define CO1   512
#define CO2   256
#define LNN   256

typedef __attribute__((ext_vector_type(8))) short bhalf8;   // 8 bf16 (4 VGPR)
typedef __attribute__((ext_vector_type(4))) float facc4;    // MFMA accumulator

#define MFMA16(a, b, c) __builtin_amdgcn_mfma_f32_16x16x32_bf16(a, b, c, 0, 0, 0)

__device__ inline unsigned short f2bf(float f) {   // round-to-nearest-even
  unsigned u = __float_as_uint(f);
  return (unsigned short)((u + 0x7FFFu + ((u >> 16) & 1u)) >> 16);
}

#if __has_builtin(__builtin_amdgcn_global_load_lds)
#define HAVE_GLDS 1
#else
#define HAVE_GLDS 0
#endif

// 1024B stage: fully per-lane global src pointer, wave-uniform LDS dest
// (HW writes dest + lane*16).  Fallback mirrors the same lane->slot map.
__device__ __forceinline__ void g2l_lane(const unsigned short* g_lane,
                                         unsigned short* l_base, int lane) {
#if HAVE_GLDS
  __builtin_amdgcn_global_load_lds(
      (const __attribute__((address_space(1))) void*)g_lane,
      (__attribute__((address_space(3))) void*)l_base, 16, 0, 0);
#else
  *(bhalf8*)(l_base + lane * 8) = *(const bhalf8*)g_lane;
#endif
}

// ws offsets (bytes); end 211,189,760 (proven available in r3/r6)
#define OFF_W1TB 0u            // 9*512*64 bf16            = 589824
#define OFF_W2P  589824u       // 8cc*3g*256o*64 bf16      = 786432
#define OFF_H0T  1474560u      // 32*2048*64 bf16          = 8388608
#define OFF_H1   9863168u      // 32*2048*512 fp32         = 134217728 ; V aliases
#define OFF_H1SQ 144080896u    // 32*8*256*512 bf16        = 67108864

// ---------------- prep: weights -> bf16 -------------------------------------
// w1tb[g][co][cb64] = bf16(w1[co][cb][g]); w2p[cc][g][o][64] = bf16(w2[o][g][c])
__global__ __launch_bounds__(256) void prep_kernel(
    const float* __restrict__ w1, const float* __restrict__ w2,
    unsigned short* __restrict__ w1tb, unsigned short* __restrict__ w2p) {
  int idx = blockIdx.x * 256 + threadIdx.x;
  if (idx < 294912) {                    // 9*512*64
    int cb = idx & 63;
    int co = (idx >> 6) & 511;
    int g  = idx >> 15;
    w1tb[idx] = f2bf(w1[(co * 64 + cb) * 9 + g]);
  } else {
    int j = idx - 294912;                // 8*3*256*64 = 393216 tasks
    int ci = j & 63;
    int t  = j >> 6;
    int o  = t & 255;
    t >>= 8;                             // t in [0,24)
    int g  = t % 3;
    int cc = t / 3;
    w2p[((cc * 3 + g) * 256 + o) * 64 + ci] =
        f2bf(w2[(o * 3 + g) * 512 + cc * 64 + ci]);
  }
}

// ---------------- conv0: 1x1, x[B][64][L] -> h0t bf16 [B][L][64] ------------
__global__ __launch_bounds__(256) void conv0_kernel(
    const float* __restrict__ x, const float* __restrict__ w0,
    const float* __restrict__ b0, unsigned short* __restrict__ h0t) {
  __shared__ __align__(16) float xt[64][128];
  __shared__ __align__(16) float w0t[64][68];
  int tid = threadIdx.x;
  int b = blockIdx.y;
  int l0 = blockIdx.x * 128;
  const float* xb = x + (size_t)b * 64 * LL;
#pragma unroll
  for (int i = 0; i < 8; i++) {
    int idx = i * 256 + tid;
    int k = idx >> 5, l4 = idx & 31;
    float4 v = *(const float4*)&xb[k * LL + l0 + l4 * 4];
    *(float4*)&xt[k][l4 * 4] = v;
  }
#pragma unroll
  for (int i = 0; i < 16; i++) {
    int idx = i * 256 + tid;
    int cb = idx >> 6, k = idx & 63;
    w0t[k][cb] = w0[idx];
  }
  __syncthreads();
  int lc = tid & 31, rc = tid >> 5;             // l=lc*4+j, cb=rc*8+i
  float acc[8][4] = {};
  for (int k = 0; k < 64; k++) {
    float4 bv = *(const float4*)&xt[k][lc * 4];
    float4 a0 = *(const float4*)&w0t[k][rc * 8];
    float4 a1 = *(const float4*)&w0t[k][rc * 8 + 4];
    float a[8] = {a0.x, a0.y, a0.z, a0.w, a1.x, a1.y, a1.z, a1.w};
    float bb4[4] = {bv.x, bv.y, bv.z, bv.w};
#pragma unroll
    for (int i = 0; i < 8; i++)
#pragma unroll
      for (int j = 0; j < 4; j++) acc[i][j] += a[i] * bb4[j];
  }
  float bias[8];
#pragma unroll
  for (int i = 0; i < 8; i++) bias[i] = b0[rc * 8 + i];
#pragma unroll
  for (int j = 0; j < 4; j++) {
    bhalf8 o;
#pragma unroll
    for (int i = 0; i < 8; i++) o[i] = (short)f2bf(acc[i][j] + bias[i]);
    *(bhalf8*)&h0t[((size_t)b * LL + l0 + lc * 4 + j) * 64 + rc * 8] = o;
  }
}

// ---------------- conv1 v3: k=9, 64->512, barrier-free main loop ------------
// block 512 thr (8 waves, 4co x 2l), out-tile 256co x 128l.  Xt staged once;
// A-frags stream from L2-resident w1tb (no Wg, no in-loop barriers).
__global__ __launch_bounds__(512) void conv1_mfma(
    const unsigned short* __restrict__ h0t, const unsigned short* __restrict__ w1tb,
    const float* __restrict__ b1, float* __restrict__ h1) {
  __shared__ __align__(16) unsigned short Xt[136 * 72];   // rows l0-4..l0+131, pad72
  int tid = threadIdx.x;
  int b = blockIdx.z;
  int co0 = blockIdx.y * 256;
  int l0 = blockIdx.x * 128;
#pragma unroll
  for (int it = 0; it < 3; it++) {                        // 1088 short8 tasks
    int idx = it * 512 + tid;
    if (idx < 1088) {
      int row = idx >> 3, c8 = (idx & 7) * 8;
      int l = l0 - 4 + row;
      bhalf8 v = (bhalf8)0;
      if (l >= 0 && l < LL) v = *(const bhalf8*)&h0t[((size_t)b * LL + l) * 64 + c8];
      *(bhalf8*)&Xt[row * 72 + c8] = v;
    }
  }
  __syncthreads();
  int wid = tid >> 6, lane = tid & 63;
  int wr = wid >> 1, wc = wid & 1;
  int r16 = lane & 15, k8 = lane >> 4;
  facc4 acc[4][4] = {};
  for (int g = 0; g < 9; g++) {
#pragma unroll
    for (int ks = 0; ks < 2; ks++) {
      bhalf8 A[4], Bf[4];
#pragma unroll
      for (int mi = 0; mi < 4; mi++)
        A[mi] = *(const bhalf8*)&w1tb[((size_t)(g * 512 + co0 + wr * 64 + mi * 16 + r16)) * 64 +
                                      ks * 32 + k8 * 8];
#pragma unroll
      for (int ni = 0; ni < 4; ni++)
        Bf[ni] = *(const bhalf8*)&Xt[(wc * 64 + ni * 16 + r16 + g) * 72 + ks * 32 + k8 * 8];
#pragma unroll
      for (int mi = 0; mi < 4; mi++)
#pragma unroll
        for (int ni = 0; ni < 4; ni++)
          acc[mi][ni] = MFMA16(A[mi], Bf[ni], acc[mi][ni]);
    }
  }
#pragma unroll
  for (int mi = 0; mi < 4; mi++) {
    int co_w = co0 + wr * 64 + mi * 16 + k8 * 4;
    float4 bias = *(const float4*)&b1[co_w];
#pragma unroll
    for (int ni = 0; ni < 4; ni++) {
      int l_w = l0 + wc * 64 + ni * 16 + r16;
      float* p = &h1[((size_t)b * LL + l_w) * CO1 + co_w];
      *(float4*)p = make_float4(acc[mi][ni][0] + bias.x, acc[mi][ni][1] + bias.y,
                                acc[mi][ni][2] + bias.z, acc[mi][ni][3] + bias.w);
    }
  }
}

// ---------------- squash: h1 fp32 -> h1sq bf16 [b][n][ln][512] --------------
__global__ __launch_bounds__(256) void squash1_kernel(
    const float* __restrict__ h1, unsigned short* __restrict__ h1sq) {
  int tid = threadIdx.x;
  int wave = tid >> 6, lane = tid & 63;
  size_t row = (size_t)blockIdx.x * 4 + wave;      // b*L + l
  const float* p = h1 + row * CO1;
  float4 v0 = *(const float4*)(p + lane * 8);
  float4 v1 = *(const float4*)(p + lane * 8 + 4);
  float sq = v0.x * v0.x + v0.y * v0.y + v0.z * v0.z + v0.w * v0.w +
             v1.x * v1.x + v1.y * v1.y + v1.z * v1.z + v1.w * v1.w;
#pragma unroll
  for (int m = 1; m < 64; m <<= 1) sq += __shfl_xor(sq, m, 64);
  float s = sq / (1.f + sq) / sqrtf(sq + 1e-8f);
  bhalf8 o;
  o[0] = (short)f2bf(v0.x * s); o[1] = (short)f2bf(v0.y * s);
  o[2] = (short)f2bf(v0.z * s); o[3] = (short)f2bf(v0.w * s);
  o[4] = (short)f2bf(v1.x * s); o[5] = (short)f2bf(v1.y * s);
  o[6] = (short)f2bf(v1.z * s); o[7] = (short)f2bf(v1.w * s);
  int b = (int)(row >> 11), l = (int)(row & 2047);
  int ln = l >> 3, n = l & 7;
  *(bhalf8*)&h1sq[((size_t)((b * 8 + n) * 256 + ln)) * 512 + lane * 8] = o;  // 1KB rows
}

// ---------------- conv2 v3: per (b,n), 256o x 256ln, 8 cc-phases ------------
// LDS = Hc only (258 x 64, 33 KB), XOR-swizzled: LDS[r][s] holds global 16B-
// slot s^(r&7) (pre-swizzled source; read applies same XOR -> conflict-free).
// A-frags stream from L2-resident w2p.
__global__ __launch_bounds__(512) void conv2_mfma(
    const unsigned short* __restrict__ h1sq, const unsigned short* __restrict__ w2p,
    const float* __restrict__ b2, float* __restrict__ V) {
  __shared__ __align__(16) unsigned short Hc[258 * 64];    // row r <-> ln = r-1
  int tid = threadIdx.x;
  int bn = blockIdx.x;
  int b = bn >> 3, n = bn & 7;
  int wid = tid >> 6, lane = tid & 63;
  int wr = wid >> 2, wc = wid & 3;                 // 2 o-halves x 4 ln-quarters
  int r16 = lane & 15, k8 = lane >> 4;
  int row8 = lane >> 3, slot = lane & 7;           // staging lane map
  facc4 acc[8][4] = {};
  const unsigned short* hbase = h1sq + (size_t)(b * 8 + n) * 256 * 512;
  for (int cc = 0; cc < 8; cc++) {
    __syncthreads();                               // prev MFMA done before overwrite
    if (tid < 128) {                               // halo rows ln=-1 (r0), ln=256 (r257)
      int r = tid >> 6, c = tid & 63;
      Hc[(r ? 257 : 0) * 64 + c] = 0;
    }
    for (int ch = wid; ch < 32; ch += 8) {         // rows 1..256 (ln 0..255)
      int r = 1 + ch * 8 + row8;                   // this lane's Hc row
      int gslot = slot ^ (r & 7);                  // inverse swizzle on SOURCE
      g2l_lane(&hbase[(size_t)(r - 1) * 512 + cc * 64 + gslot * 8],
               &Hc[(1 + ch * 8) * 64], lane);
    }
    __syncthreads();                               // drains vmcnt + lgkm
    const unsigned short* wbase = w2p + (size_t)cc * (3 * 256 * 64);
#pragma unroll
    for (int g = 0; g < 3; g++) {
#pragma unroll
      for (int ks = 0; ks < 2; ks++) {
        bhalf8 Av[8];
#pragma unroll
        for (int mi = 0; mi < 8; mi++)
          Av[mi] = *(const bhalf8*)&wbase[(size_t)(g * 256 + wr * 128 + mi * 16 + r16) * 64 +
                                          ks * 32 + k8 * 8];
        bhalf8 Bv[4];
#pragma unroll
        for (int ni = 0; ni < 4; ni++) {           // B row = ln_w + g (pad 1)
          int rr = wc * 64 + ni * 16 + r16 + g;
          int sl = (ks * 4 + k8) ^ (rr & 7);       // swizzled read slot
          Bv[ni] = *(const bhalf8*)&Hc[rr * 64 + sl * 8];
        }
#pragma unroll
        for (int mi = 0; mi < 8; mi++)
#pragma unroll
          for (int ni = 0; ni < 4; ni++)
            acc[mi][ni] = MFMA16(Av[mi], Bv[ni], acc[mi][ni]);
      }
    }
  }
#pragma unroll
  for (int mi = 0; mi < 8; mi++) {
    int o_w = wr * 128 + mi * 16 + k8 * 4;
    float4 bias = *(const float4*)&b2[o_w];
#pragma unroll
    for (int ni = 0; ni < 4; ni++) {
      int ln_w = wc * 64 + ni * 16 + r16;
      float* p = &V[(((size_t)b * LNN + ln_w) * NCAP + n) * CO2 + o_w];
      *(float4*)p = make_float4(acc[mi][ni][0] + bias.x, acc[mi][ni][1] + bias.y,
                                acc[mi][ni][2] + bias.z, acc[mi][ni][3] + bias.w);
    }
  }
}

// ---------------- dynamic routing: one block per (b,ln) ---------------------
__global__ __launch_bounds__(256) void routing_kernel(
    const float* __restrict__ V, float* __restrict__ out) {
  __shared__ float Vs[8][16][17];
  __shared__ float blog[8][16];
  __shared__ float cbuf[8][16];
  __shared__ float vbuf[16][17];
  int tid = threadIdx.x;
  size_t base = (size_t)blockIdx.x * 2048;
#pragma unroll
  for (int i = 0; i < 8; i++) {
    int idx = i * 256 + tid;
    int nn = idx >> 8, r = idx & 255;
    Vs[nn][r >> 4][r & 15] = V[base + idx];
  }
  if (tid < 128) blog[tid >> 4][tid & 15] = 0.f;
  __syncthreads();
  int csb = tid >> 4, asb = tid & 15;
  for (int r = 0; r < 3; r++) {
    if (tid < 128) {                     // softmax over csb (lane%16 = csb)
      int nn = tid >> 4, cs = tid & 15;
      float xv = blog[nn][cs];
      float m = xv;
#pragma unroll
      for (int d = 1; d < 16; d <<= 1) m = fmaxf(m, __shfl_xor(m, d, 16));
      float e = expf(xv - m);
      float ssum = e;
#pragma unroll
      for (int d = 1; d < 16; d <<= 1) ssum += __shfl_xor(ssum, d, 16);
      cbuf[nn][cs] = e / ssum;
    }
    __syncthreads();
    float s = 0.f;                       // s[csb][asb] = sum_n c*V
#pragma unroll
    for (int q = 0; q < 8; q++) s += cbuf[q][csb] * Vs[q][csb][asb];
    float sq = s * s;                    // reduce over asb
#pragma unroll
    for (int d = 1; d < 16; d <<= 1) sq += __shfl_xor(sq, d, 16);
    float vv = s * (sq / (1.f + sq) / sqrtf(sq + 1e-8f));
    if (r < 2) {
      vbuf[csb][asb] = vv;
      __syncthreads();
      if (tid < 128) {                   // a[n][csb] = sum_asb V*v
        int nn = tid >> 4, cs = tid & 15;
        float a = 0.f;
#pragma unroll
        for (int q = 0; q < 16; q++) a += Vs[nn][cs][q] * vbuf[cs][q];
        blog[nn][cs] += a;
      }
      __syncthreads();
    } else {
      out[(size_t)blockIdx.x * 256 + tid] = vv;
    }
  }
}

extern "C" void kernel_launch(void* const* d_in, const int* in_sizes, int n_in,
                              void* d_out, int out_size, void* d_ws, size_t ws_size,
                              hipStream_t stream) {
  const float* x  = (const float*)d_in[0];
  const float* w0 = (const float*)d_in[1];
  const float* b0 = (const float*)d_in[2];
  const float* w1 = (const float*)d_in[3];
  const float* b1 = (const float*)d_in[4];
  const float* w2 = (const float*)d_in[5];
  const float* b2 = (const float*)d_in[6];
  float* out = (float*)d_out;
  char* ws = (char*)d_ws;
  unsigned short* w1tb = (unsigned short*)(ws + OFF_W1TB);
  unsigned short* w2p  = (unsigned short*)(ws + OFF_W2P);
  unsigned short* h0t  = (unsigned short*)(ws + OFF_H0T);
  float*          h1   = (float*)(ws + OFF_H1);
  unsigned short* h1sq = (unsigned short*)(ws + OFF_H1SQ);
  float*          Vb   = (float*)(ws + OFF_H1);   // aliases h1 (dead after squash)

  prep_kernel<<<2688, 256, 0, stream>>>(w1, w2, w1tb, w2p);
  conv0_kernel<<<dim3(16, 32), 256, 0, stream>>>(x, w0, b0, h0t);
  conv1_mfma<<<dim3(16, 2, 32), 512, 0, stream>>>(h0t, w1tb, b1, h1);
  squash1_kernel<<<16384, 256, 0, stream>>>(h1, h1sq);
  conv2_mfma<<<256, 512, 0, stream>>>(h1sq, w2p, b2, Vb);
  routing_kernel<<<8192, 256, 0, stream>>>(Vb, out);
}

// Round 11
// 244.168 us; speedup vs baseline: 1.3608x; 1.3608x over previous
//
#include <hip/hip_runtime.h>

// ---------------------------------------------------------------------------
// Capsule cell, bf16-MFMA v4.
//   conv0 (1x1, fp32 VALU)          -> h0t  bf16 [B][L][64]
//   conv1 (k=9, MFMA, r6 structure) -> h1   fp32 [B][L][512]
//   squash                          -> h1sq bf16 [b][n][ln][512] (contig rows)
//   conv2 (k=3x512, MFMA, v4)       -> V    fp32 [B][LN][N][256]
//   routing (3 iters, fp32)         -> out  [B][LN*16][16]
// conv2 v4: 2-deep software pipeline (T3 minimal recipe): per (cc,g) phase
// STAGE(next buffers) -> COMPUTE(current) -> __syncthreads() (drains vmcnt).
// W double-buffered 32KBx2, Hc double-buffered 33KBx2; BOTH XOR-swizzled
// (slot^(row&7)) with pre-swizzled global_load_lds sources (r9: 0 conflicts).
// LDS 131KB, 1 block/CU, grid 256.  Lesson r9: MFMA operands NEVER stream
// from global - L2 latency on the MFMA path halves MfmaUtil.
// ---------------------------------------------------------------------------

#define LL    2048
#define NCAP  8
#define CO1   512
#define CO2   256
#define LNN   256

typedef __attribute__((ext_vector_type(8))) short bhalf8;   // 8 bf16 (4 VGPR)
typedef __attribute__((ext_vector_type(4))) float facc4;    // MFMA accumulator

#define MFMA16(a, b, c) __builtin_amdgcn_mfma_f32_16x16x32_bf16(a, b, c, 0, 0, 0)

__device__ inline unsigned short f2bf(float f) {   // round-to-nearest-even
  unsigned u = __float_as_uint(f);
  return (unsigned short)((u + 0x7FFFu + ((u >> 16) & 1u)) >> 16);
}

#if __has_builtin(__builtin_amdgcn_global_load_lds)
#define HAVE_GLDS 1
#else
#define HAVE_GLDS 0
#endif

// 1024B stage: per-lane global src pointer, wave-uniform LDS dest
// (HW writes dest + lane*16).  Fallback mirrors the same lane->slot map.
__device__ __forceinline__ void g2l_lane(const unsigned short* g_lane,
                                         unsigned short* l_base, int lane) {
#if HAVE_GLDS
  __builtin_amdgcn_global_load_lds(
      (const __attribute__((address_space(1))) void*)g_lane,
      (__attribute__((address_space(3))) void*)l_base, 16, 0, 0);
#else
  *(bhalf8*)(l_base + lane * 8) = *(const bhalf8*)g_lane;
#endif
}

// ws offsets (bytes); end 211,189,760 (proven available)
#define OFF_W1TB 0u            // 9*512*64 bf16            = 589824
#define OFF_W2P  589824u       // 8cc*3g*256o*64 bf16      = 786432
#define OFF_H0T  1474560u      // 32*2048*64 bf16          = 8388608
#define OFF_H1   9863168u      // 32*2048*512 fp32         = 134217728 ; V aliases
#define OFF_H1SQ 144080896u    // 32*8*256*512 bf16        = 67108864

// ---------------- prep: weights -> bf16 -------------------------------------
// w1tb[g][co][cb64] = bf16(w1[co][cb][g]); w2p[cc][g][o][64] = bf16(w2[o][g][c])
__global__ __launch_bounds__(256) void prep_kernel(
    const float* __restrict__ w1, const float* __restrict__ w2,
    unsigned short* __restrict__ w1tb, unsigned short* __restrict__ w2p) {
  int idx = blockIdx.x * 256 + threadIdx.x;
  if (idx < 294912) {                    // 9*512*64
    int cb = idx & 63;
    int co = (idx >> 6) & 511;
    int g  = idx >> 15;
    w1tb[idx] = f2bf(w1[(co * 64 + cb) * 9 + g]);
  } else {
    int j = idx - 294912;                // 8*3*256*64 = 393216 tasks
    int ci = j & 63;
    int t  = j >> 6;
    int o  = t & 255;
    t >>= 8;                             // t in [0,24)
    int g  = t % 3;
    int cc = t / 3;
    w2p[((cc * 3 + g) * 256 + o) * 64 + ci] =
        f2bf(w2[(o * 3 + g) * 512 + cc * 64 + ci]);
  }
}

// ---------------- conv0: 1x1, x[B][64][L] -> h0t bf16 [B][L][64] ------------
__global__ __launch_bounds__(256) void conv0_kernel(
    const float* __restrict__ x, const float* __restrict__ w0,
    const float* __restrict__ b0, unsigned short* __restrict__ h0t) {
  __shared__ __align__(16) float xt[64][128];
  __shared__ __align__(16) float w0t[64][68];
  int tid = threadIdx.x;
  int b = blockIdx.y;
  int l0 = blockIdx.x * 128;
  const float* xb = x + (size_t)b * 64 * LL;
#pragma unroll
  for (int i = 0; i < 8; i++) {
    int idx = i * 256 + tid;
    int k = idx >> 5, l4 = idx & 31;
    float4 v = *(const float4*)&xb[k * LL + l0 + l4 * 4];
    *(float4*)&xt[k][l4 * 4] = v;
  }
#pragma unroll
  for (int i = 0; i < 16; i++) {
    int idx = i * 256 + tid;
    int cb = idx >> 6, k = idx & 63;
    w0t[k][cb] = w0[idx];
  }
  __syncthreads();
  int lc = tid & 31, rc = tid >> 5;             // l=lc*4+j, cb=rc*8+i
  float acc[8][4] = {};
  for (int k = 0; k < 64; k++) {
    float4 bv = *(const float4*)&xt[k][lc * 4];
    float4 a0 = *(const float4*)&w0t[k][rc * 8];
    float4 a1 = *(const float4*)&w0t[k][rc * 8 + 4];
    float a[8] = {a0.x, a0.y, a0.z, a0.w, a1.x, a1.y, a1.z, a1.w};
    float bb4[4] = {bv.x, bv.y, bv.z, bv.w};
#pragma unroll
    for (int i = 0; i < 8; i++)
#pragma unroll
      for (int j = 0; j < 4; j++) acc[i][j] += a[i] * bb4[j];
  }
  float bias[8];
#pragma unroll
  for (int i = 0; i < 8; i++) bias[i] = b0[rc * 8 + i];
#pragma unroll
  for (int j = 0; j < 4; j++) {
    bhalf8 o;
#pragma unroll
    for (int i = 0; i < 8; i++) o[i] = (short)f2bf(acc[i][j] + bias[i]);
    *(bhalf8*)&h0t[((size_t)b * LL + l0 + lc * 4 + j) * 64 + rc * 8] = o;
  }
}

// ---------------- conv1: k=9, 64->512, MFMA (r6 known-good) -----------------
// block 512 thr (8 waves, 4co x 2l), out-tile 256co x 128l.
__global__ __launch_bounds__(512) void conv1_mfma(
    const unsigned short* __restrict__ h0t, const unsigned short* __restrict__ w1tb,
    const float* __restrict__ b1, float* __restrict__ h1) {
  __shared__ __align__(16) unsigned short Xt[136 * 72];   // rows l0-4..l0+131, pad72
  __shared__ __align__(16) unsigned short Wg[256 * 72];   // [co][cb pad72], per tap g
  int tid = threadIdx.x;
  int b = blockIdx.z;
  int co0 = blockIdx.y * 256;
  int l0 = blockIdx.x * 128;
#pragma unroll
  for (int it = 0; it < 3; it++) {                        // 1088 short8 tasks
    int idx = it * 512 + tid;
    if (idx < 1088) {
      int row = idx >> 3, c8 = (idx & 7) * 8;
      int l = l0 - 4 + row;
      bhalf8 v = (bhalf8)0;
      if (l >= 0 && l < LL) v = *(const bhalf8*)&h0t[((size_t)b * LL + l) * 64 + c8];
      *(bhalf8*)&Xt[row * 72 + c8] = v;
    }
  }
  int wid = tid >> 6, lane = tid & 63;
  int wr = wid >> 1, wc = wid & 1;
  int r16 = lane & 15, k8 = lane >> 4;
  facc4 acc[4][4] = {};
  for (int g = 0; g < 9; g++) {
    __syncthreads();                                      // Wg reuse + (g=0) Xt ready
#pragma unroll
    for (int it = 0; it < 4; it++) {                      // 2048 short8 tasks
      int idx = it * 512 + tid;
      int row = idx >> 3, c8 = (idx & 7) * 8;
      *(bhalf8*)&Wg[row * 72 + c8] =
          *(const bhalf8*)&w1tb[((size_t)(g * 512 + co0 + row)) * 64 + c8];
    }
    __syncthreads();
#pragma unroll
    for (int ks = 0; ks < 2; ks++) {
      bhalf8 A[4], Bf[4];
#pragma unroll
      for (int mi = 0; mi < 4; mi++)
        A[mi] = *(const bhalf8*)&Wg[(wr * 64 + mi * 16 + r16) * 72 + ks * 32 + k8 * 8];
#pragma unroll
      for (int ni = 0; ni < 4; ni++)
        Bf[ni] = *(const bhalf8*)&Xt[(wc * 64 + ni * 16 + r16 + g) * 72 + ks * 32 + k8 * 8];
#pragma unroll
      for (int mi = 0; mi < 4; mi++)
#pragma unroll
        for (int ni = 0; ni < 4; ni++)
          acc[mi][ni] = MFMA16(A[mi], Bf[ni], acc[mi][ni]);
    }
  }
#pragma unroll
  for (int mi = 0; mi < 4; mi++) {
    int co_w = co0 + wr * 64 + mi * 16 + k8 * 4;
    float4 bias = *(const float4*)&b1[co_w];
#pragma unroll
    for (int ni = 0; ni < 4; ni++) {
      int l_w = l0 + wc * 64 + ni * 16 + r16;
      float* p = &h1[((size_t)b * LL + l_w) * CO1 + co_w];
      *(float4*)p = make_float4(acc[mi][ni][0] + bias.x, acc[mi][ni][1] + bias.y,
                                acc[mi][ni][2] + bias.z, acc[mi][ni][3] + bias.w);
    }
  }
}

// ---------------- squash: h1 fp32 -> h1sq bf16 [b][n][ln][512] --------------
__global__ __launch_bounds__(256) void squash1_kernel(
    const float* __restrict__ h1, unsigned short* __restrict__ h1sq) {
  int tid = threadIdx.x;
  int wave = tid >> 6, lane = tid & 63;
  size_t row = (size_t)blockIdx.x * 4 + wave;      // b*L + l
  const float* p = h1 + row * CO1;
  float4 v0 = *(const float4*)(p + lane * 8);
  float4 v1 = *(const float4*)(p + lane * 8 + 4);
  float sq = v0.x * v0.x + v0.y * v0.y + v0.z * v0.z + v0.w * v0.w +
             v1.x * v1.x + v1.y * v1.y + v1.z * v1.z + v1.w * v1.w;
#pragma unroll
  for (int m = 1; m < 64; m <<= 1) sq += __shfl_xor(sq, m, 64);
  float s = sq / (1.f + sq) / sqrtf(sq + 1e-8f);
  bhalf8 o;
  o[0] = (short)f2bf(v0.x * s); o[1] = (short)f2bf(v0.y * s);
  o[2] = (short)f2bf(v0.z * s); o[3] = (short)f2bf(v0.w * s);
  o[4] = (short)f2bf(v1.x * s); o[5] = (short)f2bf(v1.y * s);
  o[6] = (short)f2bf(v1.z * s); o[7] = (short)f2bf(v1.w * s);
  int b = (int)(row >> 11), l = (int)(row & 2047);
  int ln = l >> 3, n = l & 7;
  *(bhalf8*)&h1sq[((size_t)((b * 8 + n) * 256 + ln)) * 512 + lane * 8] = o;  // 1KB rows
}

// ---------------- conv2 v4: per (b,n), 256o x 256ln, 24-phase pipeline ------
// Phase (cc,g): STAGE next W (and next Hc at g boundary) -> 64 MFMA from
// current buffers -> __syncthreads() (drains vmcnt: staged data ready).
// W[256][64] and Hc[258][64] both XOR-swizzled slot^(row&7), sources
// pre-swizzled so gload_lds linear dest + swizzled read match (rule #21).
__global__ __launch_bounds__(512) void conv2_mfma(
    const unsigned short* __restrict__ h1sq, const unsigned short* __restrict__ w2p,
    const float* __restrict__ b2, float* __restrict__ V) {
  __shared__ __align__(16) unsigned short HcA[258 * 64];   // row r <-> ln = r-1
  __shared__ __align__(16) unsigned short HcB[258 * 64];
  __shared__ __align__(16) unsigned short WA[256 * 64];
  __shared__ __align__(16) unsigned short WB[256 * 64];
  int tid = threadIdx.x;
  int bn = blockIdx.x;
  int b = bn >> 3, n = bn & 7;
  int wid = tid >> 6, lane = tid & 63;
  int wr = wid >> 2, wc = wid & 3;                 // 2 o-halves x 4 ln-quarters
  int r16 = lane & 15, k8 = lane >> 4;
  int row8 = lane >> 3, slot = lane & 7;           // staging lane map
  const unsigned short* hbase = h1sq + (size_t)(b * 8 + n) * 256 * 512;

  if (tid < 256) {                                 // zero halo rows, both buffers
    int q = tid >> 6, c = tid & 63;                // q: 0=(A,0) 1=(A,257) 2=(B,0) 3=(B,257)
    unsigned short* hb = (q & 2) ? HcB : HcA;
    hb[((q & 1) ? 257 : 0) * 64 + c] = 0;
  }
  // prologue: stage W(cc0,g0)->WA, Hc(cc0)->HcA
  for (int ch = wid; ch < 32; ch += 8)
    g2l_lane(&w2p[(size_t)(ch * 8 + row8) * 64 + (slot ^ row8) * 8],
             &WA[ch * 8 * 64], lane);
  for (int ch = wid; ch < 32; ch += 8) {
    int r = 1 + ch * 8 + row8;
    g2l_lane(&hbase[(size_t)(r - 1) * 512 + (slot ^ (r & 7)) * 8],
             &HcA[(1 + ch * 8) * 64], lane);
  }
  __syncthreads();

  facc4 acc[8][4] = {};
  for (int p = 0; p < 24; ++p) {
    int g = p % 3, cc = p / 3;
    if (p < 23) {                                  // STAGE next phase (issue early)
      int pn = p + 1;
      int gn = pn % 3, ccn = pn / 3;
      unsigned short* Wd = (pn & 1) ? WB : WA;
      const unsigned short* wsrc = w2p + (size_t)(ccn * 3 + gn) * 16384;
      for (int ch = wid; ch < 32; ch += 8)
        g2l_lane(&wsrc[(size_t)(ch * 8 + row8) * 64 + (slot ^ row8) * 8],
                 &Wd[ch * 8 * 64], lane);
      if (gn == 0) {
        unsigned short* Hd = (ccn & 1) ? HcB : HcA;
        for (int ch = wid; ch < 32; ch += 8) {
          int r = 1 + ch * 8 + row8;
          g2l_lane(&hbase[(size_t)(r - 1) * 512 + ccn * 64 + (slot ^ (r & 7)) * 8],
                   &Hd[(1 + ch * 8) * 64], lane);
        }
      }
    }
    const unsigned short* Wc  = (p & 1) ? WB : WA;
    const unsigned short* Hcc = (cc & 1) ? HcB : HcA;
#pragma unroll
    for (int ks = 0; ks < 2; ++ks) {
      bhalf8 Av[8], Bv[4];
#pragma unroll
      for (int mi = 0; mi < 8; mi++) {
        int rw = wr * 128 + mi * 16 + r16;         // rw&7 == r16&7
        Av[mi] = *(const bhalf8*)&Wc[rw * 64 + ((ks * 4 + k8) ^ (r16 & 7)) * 8];
      }
#pragma unroll
      for (int ni = 0; ni < 4; ni++) {             // B row = ln_w + g (pad 1)
        int rr = wc * 64 + ni * 16 + r16 + g;
        Bv[ni] = *(const bhalf8*)&Hcc[rr * 64 + ((ks * 4 + k8) ^ (rr & 7)) * 8];
      }
#pragma unroll
      for (int mi = 0; mi < 8; mi++)
#pragma unroll
        for (int ni = 0; ni < 4; ni++)
          acc[mi][ni] = MFMA16(Av[mi], Bv[ni], acc[mi][ni]);
    }
    __syncthreads();                               // drains vmcnt: next bufs ready
  }
#pragma unroll
  for (int mi = 0; mi < 8; mi++) {
    int o_w = wr * 128 + mi * 16 + k8 * 4;
    float4 bias = *(const float4*)&b2[o_w];
#pragma unroll
    for (int ni = 0; ni < 4; ni++) {
      int ln_w = wc * 64 + ni * 16 + r16;
      float* p = &V[(((size_t)b * LNN + ln_w) * NCAP + n) * CO2 + o_w];
      *(float4*)p = make_float4(acc[mi][ni][0] + bias.x, acc[mi][ni][1] + bias.y,
                                acc[mi][ni][2] + bias.z, acc[mi][ni][3] + bias.w);
    }
  }
}

// ---------------- dynamic routing: one block per (b,ln) ---------------------
__global__ __launch_bounds__(256) void routing_kernel(
    const float* __restrict__ V, float* __restrict__ out) {
  __shared__ float Vs[8][16][17];
  __shared__ float blog[8][16];
  __shared__ float cbuf[8][16];
  __shared__ float vbuf[16][17];
  int tid = threadIdx.x;
  size_t base = (size_t)blockIdx.x * 2048;
#pragma unroll
  for (int i = 0; i < 8; i++) {
    int idx = i * 256 + tid;
    int nn = idx >> 8, r = idx & 255;
    Vs[nn][r >> 4][r & 15] = V[base + idx];
  }
  if (tid < 128) blog[tid >> 4][tid & 15] = 0.f;
  __syncthreads();
  int csb = tid >> 4, asb = tid & 15;
  for (int r = 0; r < 3; r++) {
    if (tid < 128) {                     // softmax over csb (lane%16 = csb)
      int nn = tid >> 4, cs = tid & 15;
      float xv = blog[nn][cs];
      float m = xv;
#pragma unroll
      for (int d = 1; d < 16; d <<= 1) m = fmaxf(m, __shfl_xor(m, d, 16));
      float e = expf(xv - m);
      float ssum = e;
#pragma unroll
      for (int d = 1; d < 16; d <<= 1) ssum += __shfl_xor(ssum, d, 16);
      cbuf[nn][cs] = e / ssum;
    }
    __syncthreads();
    float s = 0.f;                       // s[csb][asb] = sum_n c*V
#pragma unroll
    for (int q = 0; q < 8; q++) s += cbuf[q][csb] * Vs[q][csb][asb];
    float sq = s * s;                    // reduce over asb
#pragma unroll
    for (int d = 1; d < 16; d <<= 1) sq += __shfl_xor(sq, d, 16);
    float vv = s * (sq / (1.f + sq) / sqrtf(sq + 1e-8f));
    if (r < 2) {
      vbuf[csb][asb] = vv;
      __syncthreads();
      if (tid < 128) {                   // a[n][csb] = sum_asb V*v
        int nn = tid >> 4, cs = tid & 15;
        float a = 0.f;
#pragma unroll
        for (int q = 0; q < 16; q++) a += Vs[nn][cs][q] * vbuf[cs][q];
        blog[nn][cs] += a;
      }
      __syncthreads();
    } else {
      out[(size_t)blockIdx.x * 256 + tid] = vv;
    }
  }
}

extern "C" void kernel_launch(void* const* d_in, const int* in_sizes, int n_in,
                              void* d_out, int out_size, void* d_ws, size_t ws_size,
                              hipStream_t stream) {
  const float* x  = (const float*)d_in[0];
  const float* w0 = (const float*)d_in[1];
  const float* b0 = (const float*)d_in[2];
  const float* w1 = (const float*)d_in[3];
  const float* b1 = (const float*)d_in[4];
  const float* w2 = (const float*)d_in[5];
  const float* b2 = (const float*)d_in[6];
  float* out = (float*)d_out;
  char* ws = (char*)d_ws;
  unsigned short* w1tb = (unsigned short*)(ws + OFF_W1TB);
  unsigned short* w2p  = (unsigned short*)(ws + OFF_W2P);
  unsigned short* h0t  = (unsigned short*)(ws + OFF_H0T);
  float*          h1   = (float*)(ws + OFF_H1);
  unsigned short* h1sq = (unsigned short*)(ws + OFF_H1SQ);
  float*          Vb   = (float*)(ws + OFF_H1);   // aliases h1 (dead after squash)

  prep_kernel<<<2688, 256, 0, stream>>>(w1, w2, w1tb, w2p);
  conv0_kernel<<<dim3(16, 32), 256, 0, stream>>>(x, w0, b0, h0t);
  conv1_mfma<<<dim3(16, 2, 32), 512, 0, stream>>>(h0t, w1tb, b1, h1);
  squash1_kernel<<<16384, 256, 0, stream>>>(h1, h1sq);
  conv2_mfma<<<256, 512, 0, stream>>>(h1sq, w2p, b2, Vb);
  routing_kernel<<<8192, 256, 0, stream>>>(Vb, out);
}

// Round 12
// 214.762 us; speedup vs baseline: 1.5472x; 1.1369x over previous
//
#include <hip/hip_runtime.h>

// ---------------------------------------------------------------------------
// Capsule cell, bf16-MFMA v5.
//   conv0 (1x1, fp32 VALU)            -> h0t  bf16 [B][L][64]
//   conv1+squash FUSED (k=9, MFMA)    -> h1sq bf16 [b][n][ln][512]
//   conv2 (k=3x512, MFMA, v4 proven)  -> V    fp32 [B][LN][N][256]
//   routing (3 iters, fp32)           -> out  [B][LN*16][16]
// conv1 v5: block = 512co x 128l (full capsule rows) so squash fuses in-block;
// 9 g-phases, 2-deep W double-buffer (64KBx2) via global_load_lds, both-sides
// XOR swizzle slot^(row&7) (r9/r11: 0 bank conflicts).  Eliminates h1 fp32
// (134MB write + 134MB read) and the separate squash kernel.
// conv2 v4 unchanged (dropped out of top-5 in r11).
// ---------------------------------------------------------------------------

#define LL    2048
#define NCAP  8
#define CO1   512
#define CO2   256
#define LNN   256

typedef __attribute__((ext_vector_type(8))) short bhalf8;   // 8 bf16 (4 VGPR)
typedef __attribute__((ext_vector_type(4))) float facc4;    // MFMA accumulator

#define MFMA16(a, b, c) __builtin_amdgcn_mfma_f32_16x16x32_bf16(a, b, c, 0, 0, 0)

__device__ inline unsigned short f2bf(float f) {   // round-to-nearest-even
  unsigned u = __float_as_uint(f);
  return (unsigned short)((u + 0x7FFFu + ((u >> 16) & 1u)) >> 16);
}

#if __has_builtin(__builtin_amdgcn_global_load_lds)
#define HAVE_GLDS 1
#else
#define HAVE_GLDS 0
#endif

// 1024B stage: per-lane global src pointer, wave-uniform LDS dest
// (HW writes dest + lane*16).  Fallback mirrors the same lane->slot map.
__device__ __forceinline__ void g2l_lane(const unsigned short* g_lane,
                                         unsigned short* l_base, int lane) {
#if HAVE_GLDS
  __builtin_amdgcn_global_load_lds(
      (const __attribute__((address_space(1))) void*)g_lane,
      (__attribute__((address_space(3))) void*)l_base, 16, 0, 0);
#else
  *(bhalf8*)(l_base + lane * 8) = *(const bhalf8*)g_lane;
#endif
}

// ws offsets (bytes); end 211,189,760 (proven available)
#define OFF_W1TB 0u            // 9*512*64 bf16            = 589824
#define OFF_W2P  589824u       // 8cc*3g*256o*64 bf16      = 786432
#define OFF_H0T  1474560u      // 32*2048*64 bf16          = 8388608
#define OFF_H1   9863168u      // V lives here (67MB)
#define OFF_H1SQ 144080896u    // 32*8*256*512 bf16        = 67108864

// ---------------- prep: weights -> bf16 -------------------------------------
// w1tb[g][co][cb64] = bf16(w1[co][cb][g]); w2p[cc][g][o][64] = bf16(w2[o][g][c])
__global__ __launch_bounds__(256) void prep_kernel(
    const float* __restrict__ w1, const float* __restrict__ w2,
    unsigned short* __restrict__ w1tb, unsigned short* __restrict__ w2p) {
  int idx = blockIdx.x * 256 + threadIdx.x;
  if (idx < 294912) {                    // 9*512*64
    int cb = idx & 63;
    int co = (idx >> 6) & 511;
    int g  = idx >> 15;
    w1tb[idx] = f2bf(w1[(co * 64 + cb) * 9 + g]);
  } else {
    int j = idx - 294912;                // 8*3*256*64 = 393216 tasks
    int ci = j & 63;
    int t  = j >> 6;
    int o  = t & 255;
    t >>= 8;                             // t in [0,24)
    int g  = t % 3;
    int cc = t / 3;
    w2p[((cc * 3 + g) * 256 + o) * 64 + ci] =
        f2bf(w2[(o * 3 + g) * 512 + cc * 64 + ci]);
  }
}

// ---------------- conv0: 1x1, x[B][64][L] -> h0t bf16 [B][L][64] ------------
__global__ __launch_bounds__(256) void conv0_kernel(
    const float* __restrict__ x, const float* __restrict__ w0,
    const float* __restrict__ b0, unsigned short* __restrict__ h0t) {
  __shared__ __align__(16) float xt[64][128];
  __shared__ __align__(16) float w0t[64][68];
  int tid = threadIdx.x;
  int b = blockIdx.y;
  int l0 = blockIdx.x * 128;
  const float* xb = x + (size_t)b * 64 * LL;
#pragma unroll
  for (int i = 0; i < 8; i++) {
    int idx = i * 256 + tid;
    int k = idx >> 5, l4 = idx & 31;
    float4 v = *(const float4*)&xb[k * LL + l0 + l4 * 4];
    *(float4*)&xt[k][l4 * 4] = v;
  }
#pragma unroll
  for (int i = 0; i < 16; i++) {
    int idx = i * 256 + tid;
    int cb = idx >> 6, k = idx & 63;
    w0t[k][cb] = w0[idx];
  }
  __syncthreads();
  int lc = tid & 31, rc = tid >> 5;             // l=lc*4+j, cb=rc*8+i
  float acc[8][4] = {};
  for (int k = 0; k < 64; k++) {
    float4 bv = *(const float4*)&xt[k][lc * 4];
    float4 a0 = *(const float4*)&w0t[k][rc * 8];
    float4 a1 = *(const float4*)&w0t[k][rc * 8 + 4];
    float a[8] = {a0.x, a0.y, a0.z, a0.w, a1.x, a1.y, a1.z, a1.w};
    float bb4[4] = {bv.x, bv.y, bv.z, bv.w};
#pragma unroll
    for (int i = 0; i < 8; i++)
#pragma unroll
      for (int j = 0; j < 4; j++) acc[i][j] += a[i] * bb4[j];
  }
  float bias[8];
#pragma unroll
  for (int i = 0; i < 8; i++) bias[i] = b0[rc * 8 + i];
#pragma unroll
  for (int j = 0; j < 4; j++) {
    bhalf8 o;
#pragma unroll
    for (int i = 0; i < 8; i++) o[i] = (short)f2bf(acc[i][j] + bias[i]);
    *(bhalf8*)&h0t[((size_t)b * LL + l0 + lc * 4 + j) * 64 + rc * 8] = o;
  }
}

// ---------------- conv1+squash fused: k=9, 64->512, MFMA v5 -----------------
// block 512 thr (8 waves, 4co x 2l), out-tile 512co x 128l per (b, l-tile).
// 9 g-phases: STAGE W[g+1] (64KB, other buffer) -> 64 MFMA/wave -> barrier.
// Epilogue: bias -> per-l sum(sq) (shfl + 4-wide LDS reduce) -> scale -> bf16.
__global__ __launch_bounds__(512) void conv1_fused(
    const unsigned short* __restrict__ h0t, const unsigned short* __restrict__ w1tb,
    const float* __restrict__ b1, unsigned short* __restrict__ h1sq) {
  __shared__ __align__(16) unsigned short Xt[136 * 64];   // row r <-> l = l0-4+r
  __shared__ __align__(16) unsigned short WA[512 * 64];
  __shared__ __align__(16) unsigned short WB[512 * 64];
  __shared__ float red[128][4];
  __shared__ float scl[128];
  int tid = threadIdx.x;
  int b = blockIdx.y;
  int l0 = blockIdx.x * 128;
  int wid = tid >> 6, lane = tid & 63;
  int wr = wid >> 1, wc = wid & 1;                 // 4 co-quarters x 2 l-halves
  int r16 = lane & 15, k8 = lane >> 4;
  int row8 = lane >> 3, slot = lane & 7;           // staging lane map
  {                                                // halo rows 0..3, 132..135
    int hr = tid >> 6, c = tid & 63;               // 8 rows x 64 cols
    int row = (hr < 4) ? hr : 128 + hr;
    int l = l0 - 4 + row;
    unsigned short v = 0;
    if (l >= 0 && l < LL) v = h0t[((size_t)b * LL + l) * 64 + c];
    Xt[row * 64 + ((c >> 3) ^ (row & 7)) * 8 + (c & 7)] = v;
  }
  for (int ch = wid; ch < 16; ch += 8) {           // bulk rows 4..131 (l0..l0+127)
    int row = 4 + ch * 8 + row8;
    g2l_lane(&h0t[((size_t)b * LL + (l0 - 4 + row)) * 64 + (slot ^ (row & 7)) * 8],
             &Xt[(4 + ch * 8) * 64], lane);
  }
  for (int ch = wid; ch < 64; ch += 8)             // prologue: W g=0 -> WA
    g2l_lane(&w1tb[(size_t)(ch * 8 + row8) * 64 + (slot ^ row8) * 8],
             &WA[ch * 8 * 64], lane);
  __syncthreads();

  facc4 acc[8][4] = {};
  for (int g = 0; g < 9; ++g) {
    if (g < 8) {                                   // STAGE next g (issue early)
      unsigned short* Wd = (g & 1) ? WA : WB;
      const unsigned short* wsrc = w1tb + (size_t)(g + 1) * 512 * 64;
      for (int ch = wid; ch < 64; ch += 8)
        g2l_lane(&wsrc[(size_t)(ch * 8 + row8) * 64 + (slot ^ row8) * 8],
                 &Wd[ch * 8 * 64], lane);
    }
    const unsigned short* Wc = (g & 1) ? WB : WA;
#pragma unroll
    for (int ks = 0; ks < 2; ++ks) {
      bhalf8 Av[8], Bv[4];
#pragma unroll
      for (int mi = 0; mi < 8; mi++) {
        int rw = wr * 128 + mi * 16 + r16;         // rw&7 == r16&7
        Av[mi] = *(const bhalf8*)&Wc[rw * 64 + ((ks * 4 + k8) ^ (r16 & 7)) * 8];
      }
#pragma unroll
      for (int ni = 0; ni < 4; ni++) {             // B row = l_local + g
        int rr = wc * 64 + ni * 16 + r16 + g;
        Bv[ni] = *(const bhalf8*)&Xt[rr * 64 + ((ks * 4 + k8) ^ (rr & 7)) * 8];
      }
#pragma unroll
      for (int mi = 0; mi < 8; mi++)
#pragma unroll
        for (int ni = 0; ni < 4; ni++)
          acc[mi][ni] = MFMA16(Av[mi], Bv[ni], acc[mi][ni]);
    }
    __syncthreads();                               // drains vmcnt: next buf ready
  }
  // ---- fused squash epilogue ----
  float part[4] = {0.f, 0.f, 0.f, 0.f};
#pragma unroll
  for (int mi = 0; mi < 8; mi++) {
    int co_w = wr * 128 + mi * 16 + k8 * 4;
    float4 bias = *(const float4*)&b1[co_w];
#pragma unroll
    for (int ni = 0; ni < 4; ni++) {
      acc[mi][ni][0] += bias.x; acc[mi][ni][1] += bias.y;
      acc[mi][ni][2] += bias.z; acc[mi][ni][3] += bias.w;
      part[ni] += acc[mi][ni][0] * acc[mi][ni][0] + acc[mi][ni][1] * acc[mi][ni][1] +
                  acc[mi][ni][2] * acc[mi][ni][2] + acc[mi][ni][3] * acc[mi][ni][3];
    }
  }
#pragma unroll
  for (int ni = 0; ni < 4; ni++) {                 // reduce over k8 groups (co)
    part[ni] += __shfl_xor(part[ni], 16, 64);
    part[ni] += __shfl_xor(part[ni], 32, 64);
    if (k8 == 0) red[wc * 64 + ni * 16 + r16][wr] = part[ni];
  }
  __syncthreads();
  if (tid < 128) {                                 // final 4-way reduce + scale
    float sq = red[tid][0] + red[tid][1] + red[tid][2] + red[tid][3];
    scl[tid] = sq / (1.f + sq) / sqrtf(sq + 1e-8f);
  }
  __syncthreads();
#pragma unroll
  for (int ni = 0; ni < 4; ni++) {
    int l_loc = wc * 64 + ni * 16 + r16;
    float s = scl[l_loc];
    int l_w = l0 + l_loc;
    int n = l_w & 7, ln = l_w >> 3;
    size_t rbase = ((size_t)((b * 8 + n) * 256 + ln)) * 512;
#pragma unroll
    for (int mi = 0; mi < 8; mi++) {
      int co_w = wr * 128 + mi * 16 + k8 * 4;
      ushort4 o;
      o.x = f2bf(acc[mi][ni][0] * s); o.y = f2bf(acc[mi][ni][1] * s);
      o.z = f2bf(acc[mi][ni][2] * s); o.w = f2bf(acc[mi][ni][3] * s);
      *(ushort4*)&h1sq[rbase + co_w] = o;          // 8B stores, L2 line-merged
    }
  }
}

// ---------------- conv2 v4: per (b,n), 256o x 256ln, 24-phase pipeline ------
__global__ __launch_bounds__(512) void conv2_mfma(
    const unsigned short* __restrict__ h1sq, const unsigned short* __restrict__ w2p,
    const float* __restrict__ b2, float* __restrict__ V) {
  __shared__ __align__(16) unsigned short HcA[258 * 64];   // row r <-> ln = r-1
  __shared__ __align__(16) unsigned short HcB[258 * 64];
  __shared__ __align__(16) unsigned short WA[256 * 64];
  __shared__ __align__(16) unsigned short WB[256 * 64];
  int tid = threadIdx.x;
  int bn = blockIdx.x;
  int b = bn >> 3, n = bn & 7;
  int wid = tid >> 6, lane = tid & 63;
  int wr = wid >> 2, wc = wid & 3;                 // 2 o-halves x 4 ln-quarters
  int r16 = lane & 15, k8 = lane >> 4;
  int row8 = lane >> 3, slot = lane & 7;           // staging lane map
  const unsigned short* hbase = h1sq + (size_t)(b * 8 + n) * 256 * 512;

  if (tid < 256) {                                 // zero halo rows, both buffers
    int q = tid >> 6, c = tid & 63;
    unsigned short* hb = (q & 2) ? HcB : HcA;
    hb[((q & 1) ? 257 : 0) * 64 + c] = 0;
  }
  for (int ch = wid; ch < 32; ch += 8)             // prologue: W(cc0,g0)->WA
    g2l_lane(&w2p[(size_t)(ch * 8 + row8) * 64 + (slot ^ row8) * 8],
             &WA[ch * 8 * 64], lane);
  for (int ch = wid; ch < 32; ch += 8) {           // Hc(cc0)->HcA
    int r = 1 + ch * 8 + row8;
    g2l_lane(&hbase[(size_t)(r - 1) * 512 + (slot ^ (r & 7)) * 8],
             &HcA[(1 + ch * 8) * 64], lane);
  }
  __syncthreads();

  facc4 acc[8][4] = {};
  for (int p = 0; p < 24; ++p) {
    int g = p % 3, cc = p / 3;
    if (p < 23) {                                  // STAGE next phase (issue early)
      int pn = p + 1;
      int gn = pn % 3, ccn = pn / 3;
      unsigned short* Wd = (pn & 1) ? WB : WA;
      const unsigned short* wsrc = w2p + (size_t)(ccn * 3 + gn) * 16384;
      for (int ch = wid; ch < 32; ch += 8)
        g2l_lane(&wsrc[(size_t)(ch * 8 + row8) * 64 + (slot ^ row8) * 8],
                 &Wd[ch * 8 * 64], lane);
      if (gn == 0) {
        unsigned short* Hd = (ccn & 1) ? HcB : HcA;
        for (int ch = wid; ch < 32; ch += 8) {
          int r = 1 + ch * 8 + row8;
          g2l_lane(&hbase[(size_t)(r - 1) * 512 + ccn * 64 + (slot ^ (r & 7)) * 8],
                   &Hd[(1 + ch * 8) * 64], lane);
        }
      }
    }
    const unsigned short* Wc  = (p & 1) ? WB : WA;
    const unsigned short* Hcc = (cc & 1) ? HcB : HcA;
#pragma unroll
    for (int ks = 0; ks < 2; ++ks) {
      bhalf8 Av[8], Bv[4];
#pragma unroll
      for (int mi = 0; mi < 8; mi++) {
        int rw = wr * 128 + mi * 16 + r16;         // rw&7 == r16&7
        Av[mi] = *(const bhalf8*)&Wc[rw * 64 + ((ks * 4 + k8) ^ (r16 & 7)) * 8];
      }
#pragma unroll
      for (int ni = 0; ni < 4; ni++) {             // B row = ln_w + g (pad 1)
        int rr = wc * 64 + ni * 16 + r16 + g;
        Bv[ni] = *(const bhalf8*)&Hcc[rr * 64 + ((ks * 4 + k8) ^ (rr & 7)) * 8];
      }
#pragma unroll
      for (int mi = 0; mi < 8; mi++)
#pragma unroll
        for (int ni = 0; ni < 4; ni++)
          acc[mi][ni] = MFMA16(Av[mi], Bv[ni], acc[mi][ni]);
    }
    __syncthreads();                               // drains vmcnt: next bufs ready
  }
#pragma unroll
  for (int mi = 0; mi < 8; mi++) {
    int o_w = wr * 128 + mi * 16 + k8 * 4;
    float4 bias = *(const float4*)&b2[o_w];
#pragma unroll
    for (int ni = 0; ni < 4; ni++) {
      int ln_w = wc * 64 + ni * 16 + r16;
      float* p = &V[(((size_t)b * LNN + ln_w) * NCAP + n) * CO2 + o_w];
      *(float4*)p = make_float4(acc[mi][ni][0] + bias.x, acc[mi][ni][1] + bias.y,
                                acc[mi][ni][2] + bias.z, acc[mi][ni][3] + bias.w);
    }
  }
}

// ---------------- dynamic routing: one block per (b,ln) ---------------------
__global__ __launch_bounds__(256) void routing_kernel(
    const float* __restrict__ V, float* __restrict__ out) {
  __shared__ float Vs[8][16][17];
  __shared__ float blog[8][16];
  __shared__ float cbuf[8][16];
  __shared__ float vbuf[16][17];
  int tid = threadIdx.x;
  size_t base = (size_t)blockIdx.x * 2048;
#pragma unroll
  for (int i = 0; i < 8; i++) {
    int idx = i * 256 + tid;
    int nn = idx >> 8, r = idx & 255;
    Vs[nn][r >> 4][r & 15] = V[base + idx];
  }
  if (tid < 128) blog[tid >> 4][tid & 15] = 0.f;
  __syncthreads();
  int csb = tid >> 4, asb = tid & 15;
  for (int r = 0; r < 3; r++) {
    if (tid < 128) {                     // softmax over csb (lane%16 = csb)
      int nn = tid >> 4, cs = tid & 15;
      float xv = blog[nn][cs];
      float m = xv;
#pragma unroll
      for (int d = 1; d < 16; d <<= 1) m = fmaxf(m, __shfl_xor(m, d, 16));
      float e = expf(xv - m);
      float ssum = e;
#pragma unroll
      for (int d = 1; d < 16; d <<= 1) ssum += __shfl_xor(ssum, d, 16);
      cbuf[nn][cs] = e / ssum;
    }
    __syncthreads();
    float s = 0.f;                       // s[csb][asb] = sum_n c*V
#pragma unroll
    for (int q = 0; q < 8; q++) s += cbuf[q][csb] * Vs[q][csb][asb];
    float sq = s * s;                    // reduce over asb
#pragma unroll
    for (int d = 1; d < 16; d <<= 1) sq += __shfl_xor(sq, d, 16);
    float vv = s * (sq / (1.f + sq) / sqrtf(sq + 1e-8f));
    if (r < 2) {
      vbuf[csb][asb] = vv;
      __syncthreads();
      if (tid < 128) {                   // a[n][csb] = sum_asb V*v
        int nn = tid >> 4, cs = tid & 15;
        float a = 0.f;
#pragma unroll
        for (int q = 0; q < 16; q++) a += Vs[nn][cs][q] * vbuf[cs][q];
        blog[nn][cs] += a;
      }
      __syncthreads();
    } else {
      out[(size_t)blockIdx.x * 256 + tid] = vv;
    }
  }
}

extern "C" void kernel_launch(void* const* d_in, const int* in_sizes, int n_in,
                              void* d_out, int out_size, void* d_ws, size_t ws_size,
                              hipStream_t stream) {
  const float* x  = (const float*)d_in[0];
  const float* w0 = (const float*)d_in[1];
  const float* b0 = (const float*)d_in[2];
  const float* w1 = (const float*)d_in[3];
  const float* b1 = (const float*)d_in[4];
  const float* w2 = (const float*)d_in[5];
  const float* b2 = (const float*)d_in[6];
  float* out = (float*)d_out;
  char* ws = (char*)d_ws;
  unsigned short* w1tb = (unsigned short*)(ws + OFF_W1TB);
  unsigned short* w2p  = (unsigned short*)(ws + OFF_W2P);
  unsigned short* h0t  = (unsigned short*)(ws + OFF_H0T);
  unsigned short* h1sq = (unsigned short*)(ws + OFF_H1SQ);
  float*          Vb   = (float*)(ws + OFF_H1);

  prep_kernel<<<2688, 256, 0, stream>>>(w1, w2, w1tb, w2p);
  conv0_kernel<<<dim3(16, 32), 256, 0, stream>>>(x, w0, b0, h0t);
  conv1_fused<<<dim3(16, 32), 512, 0, stream>>>(h0t, w1tb, b1, h1sq);
  conv2_mfma<<<256, 512, 0, stream>>>(h1sq, w2p, b2, Vb);
  routing_kernel<<<8192, 256, 0, stream>>>(Vb, out);
}